// Round 1
// baseline (76.358 us; speedup 1.0000x reference)
//
#include <hip/hip_runtime.h>

// DistMax: out0 = relu(d_pred * mask), out1 = mask, out2 = count
// d_pred[i,j] = sum_d max(xs[i,d], xs[j,d]) * w[d] + b
// batch SORTED, 32 graphs over 1024 rows.
//
// One block per row i (1024 blocks x 256 threads):
//   Phase A: full-row scan of batch (int4 per thread) -> mask row (float4),
//            out0 zeros where mask==0, active-range via LDS atomicMin/Max.
//            (No +/-128 window assumption - whole row scanned.)
//   Phase B: 8 lanes per active pair (each lane: 32 dims), __shfl_xor reduce.
//            All 256 lanes busy; dep chain = 32 fmas instead of 256.
//   Block 0 additionally computes count via LDS histogram.

constexpr int N   = 1024;
constexpr int EMB = 256;
constexpr int NG  = 32;

__global__ __launch_bounds__(256)
void distmax_kernel(const float* __restrict__ xs,
                    const int*   __restrict__ batch,
                    const float* __restrict__ w,
                    const float* __restrict__ bias,
                    float* __restrict__ out0,
                    float* __restrict__ maskq,
                    float* __restrict__ count_out)
{
    const int i = blockIdx.x;      // row this block owns
    const int t = threadIdx.x;

    __shared__ int s_lo, s_hi;
    __shared__ int hist[NG];       // block 0 only

    if (t == 0) { s_lo = N; s_hi = -1; }
    if (i == 0 && t < NG) hist[t] = 0;
    __syncthreads();

    const int g = batch[i];        // block-uniform

    // ---------------- phase A: mask row + out0 zeros + range ----------------
    const int  j0 = t << 2;                      // 4 consecutive columns
    const int4 b4 = ((const int4*)batch)[t];

    const float m0 = (b4.x == g && j0 + 0 != i) ? 1.f : 0.f;
    const float m1 = (b4.y == g && j0 + 1 != i) ? 1.f : 0.f;
    const float m2 = (b4.z == g && j0 + 2 != i) ? 1.f : 0.f;
    const float m3 = (b4.w == g && j0 + 3 != i) ? 1.f : 0.f;

    float* mrow = maskq + (size_t)i * N;
    float* orow = out0  + (size_t)i * N;

    ((float4*)mrow)[t] = make_float4(m0, m1, m2, m3);

    const bool anyg = (b4.x == g) | (b4.y == g) | (b4.z == g) | (b4.w == g);
    if (!anyg) {
        // common case: whole 4-wide chunk inactive -> vector zero
        ((float4*)orow)[t] = make_float4(0.f, 0.f, 0.f, 0.f);
    } else {
        // boundary chunk: zero only where mask==0 (incl. diagonal);
        // mask==1 positions are written by phase B (disjoint addresses)
        if (m0 == 0.f) orow[j0 + 0] = 0.f;
        if (m1 == 0.f) orow[j0 + 1] = 0.f;
        if (m2 == 0.f) orow[j0 + 2] = 0.f;
        if (m3 == 0.f) orow[j0 + 3] = 0.f;
        // active range detection (batch==g, including j==i)
        const int firstj = (b4.x == g) ? j0
                         : (b4.y == g) ? j0 + 1
                         : (b4.z == g) ? j0 + 2 : j0 + 3;
        const int lastj  = (b4.w == g) ? j0 + 3
                         : (b4.z == g) ? j0 + 2
                         : (b4.y == g) ? j0 + 1 : j0;
        atomicMin(&s_lo, firstj);
        atomicMax(&s_hi, lastj);
    }

    // block 0: graph-size histogram for count
    if (i == 0) {
        for (int k = t; k < N; k += 256) {
            int gg = batch[k];
            gg = gg < 0 ? 0 : (gg >= NG ? NG - 1 : gg);
            atomicAdd(&hist[gg], 1);
        }
    }
    __syncthreads();

    if (i == 0 && t == 0) {
        long long tot = 0;
        for (int q = 0; q < NG; ++q) {
            long long c = hist[q];
            tot += c * c;
        }
        count_out[0] = (float)(tot - (long long)N);  // minus diagonal
    }

    // ---------------- phase B: dots, 8 lanes per pair ----------------
    const int lo   = s_lo;
    const int nact = s_hi - lo + 1;      // contiguous (batch sorted), >= 1
    const float bv = bias[0];

    const float4* xi4 = (const float4*)(xs + (size_t)i * EMB);
    const float4* w4  = (const float4*)w;

    const int sub = t & 7;     // lane within 8-lane group
    const int grp = t >> 3;    // group 0..31 -> pair index stride 32
    const int d0  = sub << 3;  // base float4 index: 8 float4 = 32 dims

    for (int p = grp; p < nact; p += 32) {
        const int j = lo + p;            // group-uniform
        float acc = 0.f;
        if (j != i) {
            const float4* xj4 = (const float4*)(xs + (size_t)j * EMB);
            #pragma unroll
            for (int q = 0; q < 8; ++q) {
                const float4 a  = xi4[d0 + q];
                const float4 bb = xj4[d0 + q];
                const float4 wv = w4[d0 + q];
                acc = fmaf(fmaxf(a.x, bb.x), wv.x, acc);
                acc = fmaf(fmaxf(a.y, bb.y), wv.y, acc);
                acc = fmaf(fmaxf(a.z, bb.z), wv.z, acc);
                acc = fmaf(fmaxf(a.w, bb.w), wv.w, acc);
            }
        }
        // reduce across the 8-lane group (group never straddles a wave)
        acc += __shfl_xor(acc, 1);
        acc += __shfl_xor(acc, 2);
        acc += __shfl_xor(acc, 4);
        if (sub == 0 && j != i) {
            orow[j] = fmaxf(acc + bv, 0.f);
        }
    }
}

extern "C" void kernel_launch(void* const* d_in, const int* in_sizes, int n_in,
                              void* d_out, int out_size, void* d_ws, size_t ws_size,
                              hipStream_t stream)
{
    const float* xs    = (const float*)d_in[0];
    const int*   batch = (const int*)  d_in[1];
    const float* w     = (const float*)d_in[2];
    const float* bias  = (const float*)d_in[3];

    float* out0  = (float*)d_out;
    float* maskq = out0 + (size_t)N * N;
    float* cnt   = out0 + (size_t)2 * N * N;

    distmax_kernel<<<N, 256, 0, stream>>>(xs, batch, w, bias, out0, maskq, cnt);
}